// Round 3
// baseline (1149.838 us; speedup 1.0000x reference)
//
#include <hip/hip_runtime.h>

#define B_   4
#define C_   64
#define ICn  16
#define D_   8
#define H_   128
#define W_   128
#define HW_  16384
#define MID_ 4
#define HP_  64
#define L_   4096
#define F_   144
#define SCALE_ 10.0f

__device__ __forceinline__ float bf2f(unsigned short u) {
    return __uint_as_float(((unsigned)u) << 16);
}
__device__ __forceinline__ unsigned short f2bf(float x) {
    unsigned u = __float_as_uint(x);
    u += 0x7FFFu + ((u >> 16) & 1u);   // RNE
    return (unsigned short)(u >> 16);
}

// ---------------------------------------------------------------------------
// Kernel 1: three 1x1 convs on the mid depth slice. fp32 in, bf16 store
// (internal compression — threshold is 2% of max, bf16 noise is ~0.4%).
// ---------------------------------------------------------------------------
__global__ __launch_bounds__(256) void k_conv_qkv(
    const float* __restrict__ s, const float* __restrict__ g,
    const float* __restrict__ g_w, const float* __restrict__ g_b,
    const float* __restrict__ th_w, const float* __restrict__ th_b,
    const float* __restrict__ ph_w, const float* __restrict__ ph_b,
    unsigned short* __restrict__ b1, unsigned short* __restrict__ b2,
    unsigned short* __restrict__ b3)
{
    __shared__ float wq[ICn * C_], wt[ICn * C_], wp[ICn * C_];
    for (int i = threadIdx.x; i < ICn * C_; i += 256) {
        wq[i] = g_w[i]; wt[i] = th_w[i]; wp[i] = ph_w[i];
    }
    __syncthreads();

    int t = blockIdx.x * 256 + threadIdx.x;     // B_*HW_ = 65536 threads
    int hw = t & (HW_ - 1);
    int b  = t >> 14;

    float aq[ICn], at[ICn], ap[ICn];
#pragma unroll
    for (int o = 0; o < ICn; o++) { aq[o] = 0.f; at[o] = 0.f; ap[o] = 0.f; }

    for (int cc = 0; cc < C_; cc++) {
        size_t idx = ((size_t)((b * C_ + cc) * D_) + MID_) * HW_ + hw;
        float sv = s[idx];
        float gv = g[idx];
#pragma unroll
        for (int o = 0; o < ICn; o++) {
            aq[o] = fmaf(wq[o * C_ + cc], sv, aq[o]);
            at[o] = fmaf(wt[o * C_ + cc], gv, at[o]);
            ap[o] = fmaf(wp[o * C_ + cc], gv, ap[o]);
        }
    }
#pragma unroll
    for (int o = 0; o < ICn; o++) {
        b1[(size_t)(b * ICn + o) * HW_ + hw] = f2bf(aq[o] + g_b[o]);
        b2[(size_t)(b * ICn + o) * HW_ + hw] = f2bf(at[o] + th_b[o]);
        b3[(size_t)(b * ICn + o) * HW_ + hw] = f2bf(ap[o] + ph_b[o]);
    }
}

// ---------------------------------------------------------------------------
// Kernel 2: patch extraction -> bf16 flat layouts (pure bit-copy)
//   q[b][l][f], v[b][l][f] row-major; Kt[b][f][l] transposed.
//   f = c*9 + ki*3 + kj (torch-unfold channel-major order)
// ---------------------------------------------------------------------------
__global__ __launch_bounds__(256) void k_patchify(
    const unsigned short* __restrict__ b1, const unsigned short* __restrict__ b2,
    const unsigned short* __restrict__ b3,
    unsigned short* __restrict__ q, unsigned short* __restrict__ Kt,
    unsigned short* __restrict__ v)
{
    int t = blockIdx.x * 256 + threadIdx.x;     // B_*L_ = 16384
    int l = t & (L_ - 1);
    int b = t >> 12;
    int ph = l >> 6, pw = l & 63;
    size_t qbase = ((size_t)b * L_ + l) * F_;

    for (int c = 0; c < ICn; c++) {
#pragma unroll
        for (int ki = 0; ki < 3; ki++) {
            int hr = 2 * ph - 1 + ki;
#pragma unroll
            for (int kj = 0; kj < 3; kj++) {
                int wc = 2 * pw - 1 + kj;
                int f = c * 9 + ki * 3 + kj;
                unsigned short qv = 0, vv = 0, kv = 0;
                if (hr >= 0 && hr < H_ && wc >= 0 && wc < W_) {
                    size_t idx = (size_t)(b * ICn + c) * HW_ + hr * W_ + wc;
                    qv = b1[idx]; vv = b2[idx]; kv = b3[idx];
                }
                q[qbase + f] = qv;
                v[qbase + f] = vv;
                Kt[((size_t)b * F_ + f) * L_ + l] = kv;
            }
        }
    }
}

// ---------------------------------------------------------------------------
// Kernel 3: flash-style attention. bf16 global tiles -> fp32 LDS -> fp32 FMA.
// Block = 256 threads, TM=64 query rows, TN=64 keys/tile, online softmax.
// ---------------------------------------------------------------------------
#define TM 64
#define TN 64
#define QS 148
#define VS 148
#define PS 65

__global__ __launch_bounds__(256, 1) void k_attn(
    const unsigned short* __restrict__ q, const unsigned short* __restrict__ Kt,
    const unsigned short* __restrict__ v, float* __restrict__ zi)
{
    __shared__ float Qs[TM * QS];
    __shared__ float Ks[F_ * TN];      // [f][col]
    __shared__ float Vs[TN * VS];      // [key][f]
    __shared__ float Ps[TM * PS];
    __shared__ float red_max[TM * 4];
    __shared__ float red_sum[TM * 4];
    __shared__ float m_row[TM], l_row[TM], alpha_row[TM];

    int b    = blockIdx.x >> 6;
    int rb   = blockIdx.x & 63;
    int row0 = rb * TM;
    int t  = threadIdx.x;
    int tx = t & 15, ty = t >> 4;

    // load Q tile (64 x 144) once: bf16 -> fp32
    const unsigned short* qg = q + ((size_t)b * L_ + row0) * F_;
#pragma unroll
    for (int it = 0; it < 9; it++) {
        int idx4 = t + it * 256;                 // [0,2304)
        int r = idx4 / 36, f4 = idx4 - r * 36;
        ushort4 u = *(const ushort4*)(qg + (size_t)idx4 * 4);
        *(float4*)&Qs[r * QS + f4 * 4] =
            make_float4(bf2f(u.x), bf2f(u.y), bf2f(u.z), bf2f(u.w));
    }
    if (t < TM) { m_row[t] = -3.0e38f; l_row[t] = 0.f; }

    float accA[4][4], accB[4][4], accC[4];
#pragma unroll
    for (int r = 0; r < 4; r++) {
        accC[r] = 0.f;
#pragma unroll
        for (int k = 0; k < 4; k++) { accA[r][k] = 0.f; accB[r][k] = 0.f; }
    }

    int sr = t & 63, sq = t >> 6;

    for (int kt = 0; kt < L_ / TN; kt++) {
        __syncthreads();   // prev tile's PV reads of Ps/Vs done
        const unsigned short* kg = Kt + (size_t)b * F_ * L_ + (size_t)kt * TN;
#pragma unroll
        for (int it = 0; it < 9; it++) {
            int idx4 = t + it * 256;
            int f = idx4 >> 4, c4 = idx4 & 15;
            ushort4 u = *(const ushort4*)(kg + (size_t)f * L_ + c4 * 4);
            *(float4*)&Ks[f * TN + c4 * 4] =
                make_float4(bf2f(u.x), bf2f(u.y), bf2f(u.z), bf2f(u.w));
        }
        __syncthreads();

        // ---- S = Q K^T (64x64), 4x4 per thread ----
        float sacc[4][4];
#pragma unroll
        for (int r = 0; r < 4; r++)
#pragma unroll
            for (int c = 0; c < 4; c++) sacc[r][c] = 0.f;

#pragma unroll 4
        for (int fc = 0; fc < 36; fc++) {
            float4 q4[4], k4[4];
#pragma unroll
            for (int r = 0; r < 4; r++) q4[r] = *(const float4*)&Qs[(4 * ty + r) * QS + fc * 4];
#pragma unroll
            for (int d = 0; d < 4; d++) k4[d] = *(const float4*)&Ks[(fc * 4 + d) * TN + 4 * tx];
#pragma unroll
            for (int r = 0; r < 4; r++) {
                sacc[r][0] = fmaf(q4[r].x, k4[0].x, fmaf(q4[r].y, k4[1].x, fmaf(q4[r].z, k4[2].x, fmaf(q4[r].w, k4[3].x, sacc[r][0]))));
                sacc[r][1] = fmaf(q4[r].x, k4[0].y, fmaf(q4[r].y, k4[1].y, fmaf(q4[r].z, k4[2].y, fmaf(q4[r].w, k4[3].y, sacc[r][1]))));
                sacc[r][2] = fmaf(q4[r].x, k4[0].z, fmaf(q4[r].y, k4[1].z, fmaf(q4[r].z, k4[2].z, fmaf(q4[r].w, k4[3].z, sacc[r][2]))));
                sacc[r][3] = fmaf(q4[r].x, k4[0].w, fmaf(q4[r].y, k4[1].w, fmaf(q4[r].z, k4[2].w, fmaf(q4[r].w, k4[3].w, sacc[r][3]))));
            }
        }
#pragma unroll
        for (int r = 0; r < 4; r++)
#pragma unroll
            for (int c = 0; c < 4; c++)
                Ps[(4 * ty + r) * PS + 4 * tx + c] = sacc[r][c] * SCALE_;

        // prefetch V tile (bf16) into registers
        ushort4 vld[9];
        const unsigned short* vg = v + ((size_t)b * L_ + (size_t)kt * TN) * F_;
#pragma unroll
        for (int it = 0; it < 9; it++)
            vld[it] = *(const ushort4*)(vg + (size_t)(t + it * 256) * 4);

        __syncthreads();   // Ps visible

        // ---- online softmax: row sr, quarter sq ----
        float pmax = -3.0e38f;
#pragma unroll
        for (int i = 0; i < 16; i++) pmax = fmaxf(pmax, Ps[sr * PS + sq * 16 + i]);
        red_max[sr * 4 + sq] = pmax;
        __syncthreads();
        float tmax = fmaxf(fmaxf(red_max[sr * 4 + 0], red_max[sr * 4 + 1]),
                           fmaxf(red_max[sr * 4 + 2], red_max[sr * 4 + 3]));
        float m_old_v = m_row[sr];
        float m_new = fmaxf(m_old_v, tmax);   // idempotent under the benign m_row race
        if (sq == 0) { m_row[sr] = m_new; alpha_row[sr] = __expf(m_old_v - m_new); }
        float psum = 0.f;
#pragma unroll
        for (int i = 0; i < 16; i++) {
            float e = __expf(Ps[sr * PS + sq * 16 + i] - m_new);
            Ps[sr * PS + sq * 16 + i] = e;
            psum += e;
        }
        red_sum[sr * 4 + sq] = psum;

        // write prefetched V (bf16 -> fp32) into LDS
#pragma unroll
        for (int it = 0; it < 9; it++) {
            int idx4 = t + it * 256;
            int j = idx4 / 36, f4 = idx4 - j * 36;
            ushort4 u = vld[it];
            *(float4*)&Vs[j * VS + f4 * 4] =
                make_float4(bf2f(u.x), bf2f(u.y), bf2f(u.z), bf2f(u.w));
        }
        __syncthreads();   // Ps(exp), Vs, red_sum, alpha_row visible

        if (t < TM)
            l_row[t] = l_row[t] * alpha_row[t] +
                       red_sum[t * 4 + 0] + red_sum[t * 4 + 1] + red_sum[t * 4 + 2] + red_sum[t * 4 + 3];

        // ---- PV: acc = acc*alpha + P @ V ----
        float al[4];
#pragma unroll
        for (int r = 0; r < 4; r++) al[r] = alpha_row[4 * ty + r];
#pragma unroll
        for (int r = 0; r < 4; r++) {
            accC[r] *= al[r];
#pragma unroll
            for (int k = 0; k < 4; k++) { accA[r][k] *= al[r]; accB[r][k] *= al[r]; }
        }
#pragma unroll 4
        for (int j = 0; j < TN; j++) {
            float4 va = *(const float4*)&Vs[j * VS + 4 * tx];
            float4 vb = *(const float4*)&Vs[j * VS + 64 + 4 * tx];
            float  vc = Vs[j * VS + 128 + tx];
#pragma unroll
            for (int r = 0; r < 4; r++) {
                float p = Ps[(4 * ty + r) * PS + j];
                accA[r][0] = fmaf(p, va.x, accA[r][0]);
                accA[r][1] = fmaf(p, va.y, accA[r][1]);
                accA[r][2] = fmaf(p, va.z, accA[r][2]);
                accA[r][3] = fmaf(p, va.w, accA[r][3]);
                accB[r][0] = fmaf(p, vb.x, accB[r][0]);
                accB[r][1] = fmaf(p, vb.y, accB[r][1]);
                accB[r][2] = fmaf(p, vb.z, accB[r][2]);
                accB[r][3] = fmaf(p, vb.w, accB[r][3]);
                accC[r]    = fmaf(p, vc,  accC[r]);
            }
        }
    }

    __syncthreads();
#pragma unroll
    for (int r = 0; r < 4; r++) {
        int row = 4 * ty + r;
        float inv = 1.0f / l_row[row];
        size_t base = ((size_t)b * L_ + row0 + row) * F_;
        float4 oa = make_float4(accA[r][0] * inv, accA[r][1] * inv, accA[r][2] * inv, accA[r][3] * inv);
        float4 ob = make_float4(accB[r][0] * inv, accB[r][1] * inv, accB[r][2] * inv, accB[r][3] * inv);
        *(float4*)&zi[base + 4 * tx] = oa;
        *(float4*)&zi[base + 64 + 4 * tx] = ob;
        zi[base + 128 + tx] = accC[r] * inv;
    }
}

// ---------------------------------------------------------------------------
// Kernel 4: fold (overlap-add) + mask normalization.
// ---------------------------------------------------------------------------
__global__ __launch_bounds__(256) void k_fold(
    const float* __restrict__ zi, float* __restrict__ z)
{
    int t = blockIdx.x * 256 + threadIdx.x;   // B_*ICn*HW_ = 1,048,576
    int hw = t & (HW_ - 1);
    int h = hw >> 7, w = hw & 127;
    int ic = (t >> 14) & 15;
    int b  = t >> 18;
    int hh = h + 1, ww = w + 1;

    int iArr[2], phArr[2], nh = 0;
#pragma unroll
    for (int i = 0; i < 3; i++) {
        int u = hh - i;
        if (u >= 0 && (u & 1) == 0 && (u >> 1) < HP_) { iArr[nh] = i; phArr[nh] = u >> 1; nh++; }
    }
    int jArr[2], pwArr[2], nw = 0;
#pragma unroll
    for (int j = 0; j < 3; j++) {
        int u = ww - j;
        if (u >= 0 && (u & 1) == 0 && (u >> 1) < HP_) { jArr[nw] = j; pwArr[nw] = u >> 1; nw++; }
    }
    float acc = 0.f;
    for (int a = 0; a < nh; a++)
        for (int c2 = 0; c2 < nw; c2++) {
            int l = phArr[a] * 64 + pwArr[c2];
            acc += zi[((size_t)b * L_ + l) * F_ + ic * 9 + iArr[a] * 3 + jArr[c2]];
        }
    z[t] = acc / (float)(nh * nw);
}

// ---------------------------------------------------------------------------
// Kernel 5: out = s + W_w @ z + W_bias, broadcast over D. fp32 in/out,
// 8 elements (32 B) per thread.
// ---------------------------------------------------------------------------
__global__ __launch_bounds__(256) void k_out(
    const float* __restrict__ s, const float* __restrict__ z,
    const float* __restrict__ Ww, const float* __restrict__ Wb,
    float* __restrict__ out)
{
    int t = blockIdx.x * 256 + threadIdx.x;   // 4,194,304 threads
    size_t e0 = (size_t)t * 8;
    int hw = (int)(e0 & (HW_ - 1));
    int c  = (int)((e0 >> 17) & 63);
    int b  = (int)(e0 >> 23);

    float bias = Wb[c];
    float acc[8];
#pragma unroll
    for (int i = 0; i < 8; i++) acc[i] = bias;

    const float* zb = z + (size_t)b * ICn * HW_ + hw;
#pragma unroll
    for (int ic = 0; ic < ICn; ic++) {
        float wv = Ww[c * ICn + ic];
        const float4* zp = (const float4*)(zb + (size_t)ic * HW_);
        float4 z0 = zp[0], z1 = zp[1];
        acc[0] = fmaf(wv, z0.x, acc[0]); acc[1] = fmaf(wv, z0.y, acc[1]);
        acc[2] = fmaf(wv, z0.z, acc[2]); acc[3] = fmaf(wv, z0.w, acc[3]);
        acc[4] = fmaf(wv, z1.x, acc[4]); acc[5] = fmaf(wv, z1.y, acc[5]);
        acc[6] = fmaf(wv, z1.z, acc[6]); acc[7] = fmaf(wv, z1.w, acc[7]);
    }

    const float4* sp = (const float4*)(s + e0);
    float4 s0 = sp[0], s1 = sp[1];
    float4 o0 = make_float4(s0.x + acc[0], s0.y + acc[1], s0.z + acc[2], s0.w + acc[3]);
    float4 o1 = make_float4(s1.x + acc[4], s1.y + acc[5], s1.z + acc[6], s1.w + acc[7]);
    float4* op = (float4*)(out + e0);
    op[0] = o0; op[1] = o1;
}

// ---------------------------------------------------------------------------
extern "C" void kernel_launch(void* const* d_in, const int* in_sizes, int n_in,
                              void* d_out, int out_size, void* d_ws, size_t ws_size,
                              hipStream_t stream)
{
    (void)in_sizes; (void)n_in; (void)out_size; (void)ws_size;
    const float* s    = (const float*)d_in[0];
    const float* g    = (const float*)d_in[1];
    const float* g_w  = (const float*)d_in[2];
    const float* g_b  = (const float*)d_in[3];
    const float* th_w = (const float*)d_in[4];
    const float* th_b = (const float*)d_in[5];
    const float* ph_w = (const float*)d_in[6];
    const float* ph_b = (const float*)d_in[7];
    const float* W_w  = (const float*)d_in[8];
    const float* W_b  = (const float*)d_in[9];
    float* out = (float*)d_out;

    // Workspace layout (total ~28.5 MB; zz overlays the dead conv planes):
    //   [0,2M)    b1 bf16      [2M,4M)   b2 bf16      [4M,6M)   b3 bf16
    //   [6M,10.5M)   q bf16    [10.5M,15M) Kt bf16    [15M,19.5M) v bf16
    //   [19.5M,28.5M) zi fp32
    //   [0,4M)    zz fp32 (after patchify, conv planes are dead)
    char* base = (char*)d_ws;
    const size_t CONV_B = 2097152;    // 1,048,576 bf16
    const size_t QKV_B  = 4718592;    // 2,359,296 bf16
    unsigned short* b1 = (unsigned short*)(base);
    unsigned short* b2 = (unsigned short*)(base + CONV_B);
    unsigned short* b3 = (unsigned short*)(base + 2 * CONV_B);
    unsigned short* qq = (unsigned short*)(base + 3 * CONV_B);
    unsigned short* Kt = (unsigned short*)(base + 3 * CONV_B + QKV_B);
    unsigned short* vv = (unsigned short*)(base + 3 * CONV_B + 2 * QKV_B);
    float*          zi = (float*)(base + 3 * CONV_B + 3 * QKV_B);
    float*          zz = (float*)(base);

    hipLaunchKernelGGL(k_conv_qkv, dim3(256),   dim3(256), 0, stream,
                       s, g, g_w, g_b, th_w, th_b, ph_w, ph_b, b1, b2, b3);
    hipLaunchKernelGGL(k_patchify, dim3(64),    dim3(256), 0, stream, b1, b2, b3, qq, Kt, vv);
    hipLaunchKernelGGL(k_attn,     dim3(256),   dim3(256), 0, stream, qq, Kt, vv, zi);
    hipLaunchKernelGGL(k_fold,     dim3(4096),  dim3(256), 0, stream, zi, zz);
    hipLaunchKernelGGL(k_out,      dim3(16384), dim3(256), 0, stream, s, zz, W_w, W_b, out);
}